// Round 15
// baseline (332.297 us; speedup 1.0000x reference)
//
#include <hip/hip_runtime.h>
#include <hip/hip_bf16.h>
#include <cstdint>
#include <cstddef>

#define SDIM 128
#define EPB2 4096   // edges per block in bucket_k
#define BCAP 4608   // per-bucket capacity (mean 4092 + 8 sigma)

typedef short bf16x8 __attribute__((ext_vector_type(8)));
typedef float f32x4 __attribute__((ext_vector_type(4)));

__device__ __forceinline__ unsigned short f2bf(float f) {
  unsigned int u = __float_as_uint(f);
  unsigned int r = (u + 0x7FFF + ((u >> 16) & 1)) >> 16;  // RNE
  return (unsigned short)r;
}
__device__ __forceinline__ float bf2f(unsigned short b) {
  return __uint_as_float(((unsigned int)b) << 16);
}

// ---------------- phase 1: bucket packed (d<<16|src) by dst>>7, capacity regions ----
__global__ __launch_bounds__(256) void bucket_k(const int* __restrict__ src,
                                                const int* __restrict__ dst,
                                                int* __restrict__ bcursor,
                                                unsigned int* __restrict__ pairBuf4,
                                                int E) {
  __shared__ unsigned int s_buf[EPB2];
  __shared__ int cnt[512], base[512], gbase[512];
  const int tid = threadIdx.x;
  const int e0 = blockIdx.x * EPB2;
  const int n = min(EPB2, E - e0);
  cnt[tid] = 0; cnt[tid + 256] = 0;
  __syncthreads();

  unsigned int pack_r[16];
  int rank_r[16], bkt_r[16];
  if (n == EPB2) {
    const int4* dp = (const int4*)(dst + e0 + tid * 16);
    const int4* sp = (const int4*)(src + e0 + tid * 16);
#pragma unroll
    for (int q = 0; q < 4; ++q) {
      const int4 dv = dp[q];
      const int4 sv = sp[q];
      const int dd[4] = {dv.x, dv.y, dv.z, dv.w};
      const int ss[4] = {sv.x, sv.y, sv.z, sv.w};
#pragma unroll
      for (int w = 0; w < 4; ++w) {
        const int u = q * 4 + w;
        const int b = dd[w] >> 7;
        bkt_r[u] = b;
        pack_r[u] = ((unsigned int)dd[w] << 16) | (unsigned int)ss[w];
        rank_r[u] = atomicAdd(&cnt[b], 1);
      }
    }
  } else {
#pragma unroll
    for (int u = 0; u < 16; ++u) {
      const int li = u * 256 + tid;
      bkt_r[u] = -1;
      if (li < n) {
        const int i = e0 + li;
        const int d = dst[i];
        const int b = d >> 7;
        bkt_r[u] = b;
        pack_r[u] = ((unsigned int)d << 16) | (unsigned int)src[i];
        rank_r[u] = atomicAdd(&cnt[b], 1);
      }
    }
  }
  __syncthreads();
  if (tid < 64) {
    int carry = 0;
#pragma unroll
    for (int chunk = 0; chunk < 512; chunk += 256) {
      const int j0 = chunk + tid * 4;
      const int c0 = cnt[j0], c1 = cnt[j0 + 1], c2 = cnt[j0 + 2], c3 = cnt[j0 + 3];
      const int s = c0 + c1 + c2 + c3;
      int incl = s;
#pragma unroll
      for (int off = 1; off < 64; off <<= 1) {
        int u = __shfl_up(incl, off, 64);
        if (tid >= off) incl += u;
      }
      const int e = carry + incl - s;
      base[j0] = e;
      base[j0 + 1] = e + c0;
      base[j0 + 2] = e + c0 + c1;
      base[j0 + 3] = e + c0 + c1 + c2;
      carry += __shfl(incl, 63, 64);
    }
  }
  __syncthreads();
  for (int b = tid; b < 512; b += 256)
    if (cnt[b] > 0) gbase[b] = atomicAdd(&bcursor[b], cnt[b]);
  __syncthreads();
#pragma unroll
  for (int u = 0; u < 16; ++u) {
    if (n == EPB2 || bkt_r[u] >= 0)
      s_buf[base[bkt_r[u]] + rank_r[u]] = pack_r[u];
  }
  __syncthreads();
  for (int i = tid; i < n; i += 256) {
    const unsigned int p = s_buf[i];
    const int b = (int)(p >> 23);
    pairBuf4[(size_t)b * BCAP + (size_t)(gbase[b] + (i - base[b]))] = p;
  }
}

// ---------------- phase 2: per-bucket hist + scan + rank/scatter (padded csr) -----
__global__ __launch_bounds__(512) void fill3_k(const unsigned int* __restrict__ pairBuf4,
                                               const int* __restrict__ bcursor,
                                               int* __restrict__ offs,
                                               int* __restrict__ oend,
                                               unsigned short* __restrict__ csr, int N) {
  const int b = blockIdx.x;
  const int rlo = b * BCAP;
  const int rhi = rlo + bcursor[b];
  const int lo_node = b << 7;
  __shared__ int hist[128], cur[128];
  const int tid = threadIdx.x;
  if (tid < 128) hist[tid] = 0;
  __syncthreads();
  for (int i = rlo + tid; i < rhi; i += 512)
    atomicAdd(&hist[(pairBuf4[i] >> 16) & 127], 1);
  __syncthreads();
  if (tid < 64) {
    const int j0 = tid * 2;
    const int h0 = hist[j0], h1 = hist[j0 + 1];
    const int s = h0 + h1;
    int incl = s;
#pragma unroll
    for (int off = 1; off < 64; off <<= 1) {
      int u = __shfl_up(incl, off, 64);
      if (tid >= off) incl += u;
    }
    const int e = rlo + incl - s;
    cur[j0] = e; cur[j0 + 1] = e + h0;
    const int n0 = lo_node + j0;
    if (n0 < N) { offs[n0] = e; oend[n0] = e + h0; }
    if (n0 + 1 < N) { offs[n0 + 1] = e + h0; oend[n0 + 1] = e + h0 + h1; }
  }
  __syncthreads();
  for (int i = rlo + tid; i < rhi; i += 512) {
    const unsigned int p = pairBuf4[i];
    const int pos = atomicAdd(&cur[(p >> 16) & 127], 1);
    csr[pos] = (unsigned short)p;
  }
}

// ---------------- fused weight cast + compute_c + bcursor zero --------------------
__global__ __launch_bounds__(256) void cast2c_k(const float* __restrict__ a,
                                                const float* __restrict__ b,
                                                unsigned short* __restrict__ out, int n,
                                                const float* __restrict__ W_upd0,
                                                const float* __restrict__ b_msg0,
                                                float* __restrict__ cvec,
                                                int* __restrict__ bcursor, int NB,
                                                int nCast) {
  if ((int)blockIdx.x == nCast) {
    __shared__ float m0[SDIM];
    const int j = threadIdx.x;
    if (j < SDIM) m0[j] = fmaxf(b_msg0[j], 0.f);
    __syncthreads();
    if (j < SDIM) {
      float s = 0.f;
      const float* wr = W_upd0 + (size_t)j * SDIM;
      for (int k = 0; k < SDIM; ++k) s += wr[k] * m0[k];
      cvec[j] = s;
    }
    return;
  }
  if ((int)blockIdx.x == nCast + 1) {
    for (int i = threadIdx.x; i < NB; i += 256) bcursor[i] = 0;
    return;
  }
  int i = (blockIdx.x * 256 + threadIdx.x) * 4;
  if (i >= 2 * n) return;
  const float* s = (i < n) ? (a + i) : (b + (i - n));
  float4 v = *(const float4*)s;
  ushort4 o;
  o.x = f2bf(v.x); o.y = f2bf(v.y); o.z = f2bf(v.z); o.w = f2bf(v.w);
  *(ushort4*)(out + i) = o;
}

// ---------------- fused init_state + first message GEMM (8 waves x 16 rows) -------
__global__ __launch_bounds__(512) void initmsg_k(const int* __restrict__ offs,
                                                 const int* __restrict__ oend,
                                                 const float* __restrict__ cvec,
                                                 const float* __restrict__ bu0,
                                                 const unsigned short* __restrict__ Wm,
                                                 const float* __restrict__ bm,
                                                 unsigned short* __restrict__ sbf,
                                                 unsigned short* __restrict__ msgb, int N) {
  __shared__ unsigned short sT[8][16][136];
  const int tid = threadIdx.x, lane = tid & 63, wid = tid >> 6;
  const int r0 = blockIdx.x * 128 + wid * 16;
  int arow = r0 + (lane & 15);
  const bool rowOk = arow < N;
  if (!rowOk) arow = N - 1;
  const int kb = (lane >> 4) * 8;
  const float dn = (float)(oend[arow] - offs[arow]);

  bf16x8 a[4];
#pragma unroll
  for (int ks = 0; ks < 4; ++ks) {
    const int c0 = ks * 32 + kb;
#pragma unroll
    for (int q = 0; q < 8; ++q) {
      const float v = fmaxf(dn * cvec[c0 + q] + bu0[c0 + q], 0.f);
      a[ks][q] = (short)f2bf(v);
    }
    if (rowOk) *(bf16x8*)(sbf + (size_t)arow * SDIM + c0) = a[ks];
  }

  f32x4 acc[8];
#pragma unroll
  for (int jt = 0; jt < 8; ++jt) acc[jt] = (f32x4){0.f, 0.f, 0.f, 0.f};
  const int wrow = lane & 15;
#pragma unroll
  for (int ks = 0; ks < 4; ++ks) {
#pragma unroll
    for (int jt = 0; jt < 8; ++jt) {
      bf16x8 b = *(const bf16x8*)(Wm + (size_t)(jt * 16 + wrow) * SDIM + ks * 32 + kb);
      acc[jt] = __builtin_amdgcn_mfma_f32_16x16x32_bf16(a[ks], b, acc[jt], 0, 0, 0);
    }
  }
  const int colw = lane & 15;
  const int rt0 = (lane >> 4) * 4;
#pragma unroll
  for (int jt = 0; jt < 8; ++jt) {
    const float bj = bm[jt * 16 + colw];
#pragma unroll
    for (int r = 0; r < 4; ++r)
      sT[wid][rt0 + r][jt * 16 + colw] = f2bf(fmaxf(acc[jt][r] + bj, 0.f));
  }
  __syncthreads();
  const int vr = lane >> 4;
  const int vc = (lane & 15) * 8;
#pragma unroll
  for (int it = 0; it < 4; ++it) {
    const int lr = it * 4 + vr;
    const int row = r0 + lr;
    if (row < N)
      *(bf16x8*)(msgb + (size_t)row * SDIM + vc) = *(const bf16x8*)&sT[wid][lr][vc];
  }
}

// ---------------- fused update GEMM + (optional) next message GEMM (8 waves) ------
template <bool MSG>
__global__ __launch_bounds__(512) void updmsg_k(const unsigned short* __restrict__ aggb,
                                                const unsigned short* __restrict__ Wu,
                                                const float* __restrict__ bu,
                                                unsigned short* __restrict__ sbf,
                                                const unsigned short* __restrict__ Wm,
                                                const float* __restrict__ bm,
                                                unsigned short* __restrict__ msgb, int N) {
  __shared__ unsigned short sT[8][16][136];
  const int tid = threadIdx.x, lane = tid & 63, wid = tid >> 6;
  const int r0 = blockIdx.x * 128 + wid * 16;
  int arow = r0 + (lane & 15);
  if (arow >= N) arow = N - 1;
  const int kb = (lane >> 4) * 8;

  f32x4 acc[8];
#pragma unroll
  for (int jt = 0; jt < 8; ++jt) acc[jt] = (f32x4){0.f, 0.f, 0.f, 0.f};
  bf16x8 a[4];
#pragma unroll
  for (int ks = 0; ks < 4; ++ks)
    a[ks] = *(const bf16x8*)(aggb + (size_t)arow * SDIM + ks * 32 + kb);
  const int wrow = lane & 15;
#pragma unroll
  for (int ks = 0; ks < 4; ++ks) {
#pragma unroll
    for (int jt = 0; jt < 8; ++jt) {
      bf16x8 b = *(const bf16x8*)(Wu + (size_t)(jt * 16 + wrow) * SDIM + ks * 32 + kb);
      acc[jt] = __builtin_amdgcn_mfma_f32_16x16x32_bf16(a[ks], b, acc[jt], 0, 0, 0);
    }
  }

  const int colw = lane & 15;
  const int rt0 = (lane >> 4) * 4;
#pragma unroll
  for (int jt = 0; jt < 8; ++jt) {
    const float bj = bu[jt * 16 + colw];
#pragma unroll
    for (int r = 0; r < 4; ++r)
      sT[wid][rt0 + r][jt * 16 + colw] = f2bf(fmaxf(acc[jt][r] + bj, 0.f));
  }
  __syncthreads();

  const int vr = lane >> 4;
  const int vc = (lane & 15) * 8;
#pragma unroll
  for (int it = 0; it < 4; ++it) {
    const int lr = it * 4 + vr;
    const int row = r0 + lr;
    if (row < N) {
      bf16x8 nw = *(const bf16x8*)&sT[wid][lr][vc];
      bf16x8 old = *(const bf16x8*)(sbf + (size_t)row * SDIM + vc);
      bf16x8 up;
#pragma unroll
      for (int q = 0; q < 8; ++q)
        up[q] = (short)f2bf(bf2f((unsigned short)old[q]) + bf2f((unsigned short)nw[q]));
      *(bf16x8*)(sbf + (size_t)row * SDIM + vc) = up;
      if (MSG) *(bf16x8*)&sT[wid][lr][vc] = up;
    }
  }

  if (MSG) {
    __syncthreads();
    f32x4 acc2[8];
#pragma unroll
    for (int jt = 0; jt < 8; ++jt) acc2[jt] = (f32x4){0.f, 0.f, 0.f, 0.f};
#pragma unroll
    for (int ks = 0; ks < 4; ++ks) {
      bf16x8 a2 = *(const bf16x8*)&sT[wid][lane & 15][ks * 32 + kb];
#pragma unroll
      for (int jt = 0; jt < 8; ++jt) {
        bf16x8 b = *(const bf16x8*)(Wm + (size_t)(jt * 16 + wrow) * SDIM + ks * 32 + kb);
        acc2[jt] = __builtin_amdgcn_mfma_f32_16x16x32_bf16(a2, b, acc2[jt], 0, 0, 0);
      }
    }
    __syncthreads();  // all A-frag reads done before overwrite
#pragma unroll
    for (int jt = 0; jt < 8; ++jt) {
      const float bj = bm[jt * 16 + colw];
#pragma unroll
      for (int r = 0; r < 4; ++r)
        sT[wid][rt0 + r][jt * 16 + colw] = f2bf(fmaxf(acc2[jt][r] + bj, 0.f));
    }
    __syncthreads();
#pragma unroll
    for (int it = 0; it < 4; ++it) {
      const int lr = it * 4 + vr;
      const int row = r0 + lr;
      if (row < N)
        *(bf16x8*)(msgb + (size_t)row * SDIM + vc) = *(const bf16x8*)&sT[wid][lr][vc];
    }
  }
}

// ---------------- bf16 CSR aggregation: 32-bit offsets, 16-edge unroll ------------
__global__ __launch_bounds__(256) void agg_bf16_k(const unsigned short* __restrict__ msg,
                                                  const unsigned short* __restrict__ csr,
                                                  const int* __restrict__ offs,
                                                  const int* __restrict__ oend,
                                                  unsigned short* __restrict__ aggb, int N) {
  const int wid = (blockIdx.x * 256 + threadIdx.x) >> 6;
  if (wid >= N) return;
  const int lane = threadIdx.x & 63;
  const int grp = lane >> 4;
  const unsigned int lb = (unsigned int)((lane & 15) << 4);
  const char* base = (const char*)msg;
  const int e1 = oend[wid];
  int e = offs[wid];
  float a0 = 0.f, a1 = 0.f, a2 = 0.f, a3 = 0.f, a4 = 0.f, a5 = 0.f, a6 = 0.f, a7 = 0.f;
#define ACC8(v) { \
  a0 += __uint_as_float((v).x << 16); a1 += __uint_as_float((v).x & 0xFFFF0000u); \
  a2 += __uint_as_float((v).y << 16); a3 += __uint_as_float((v).y & 0xFFFF0000u); \
  a4 += __uint_as_float((v).z << 16); a5 += __uint_as_float((v).z & 0xFFFF0000u); \
  a6 += __uint_as_float((v).w << 16); a7 += __uint_as_float((v).w & 0xFFFF0000u); }
  for (; e + 16 <= e1; e += 16) {
    const unsigned int o0 = ((unsigned int)csr[e + grp] << 8) | lb;
    const unsigned int o1 = ((unsigned int)csr[e + 4 + grp] << 8) | lb;
    const unsigned int o2 = ((unsigned int)csr[e + 8 + grp] << 8) | lb;
    const unsigned int o3 = ((unsigned int)csr[e + 12 + grp] << 8) | lb;
    uint4 vA = *(const uint4*)(base + o0);
    uint4 vB = *(const uint4*)(base + o1);
    uint4 vC = *(const uint4*)(base + o2);
    uint4 vD = *(const uint4*)(base + o3);
    ACC8(vA) ACC8(vB) ACC8(vC) ACC8(vD)
  }
  for (; e + 4 <= e1; e += 4) {
    const unsigned int o0 = ((unsigned int)csr[e + grp] << 8) | lb;
    uint4 v = *(const uint4*)(base + o0);
    ACC8(v)
  }
  if (e + grp < e1) {
    const unsigned int o0 = ((unsigned int)csr[e + grp] << 8) | lb;
    uint4 v = *(const uint4*)(base + o0);
    ACC8(v)
  }
#undef ACC8
#define RED(x) x += __shfl_xor(x, 16, 64); x += __shfl_xor(x, 32, 64);
  RED(a0) RED(a1) RED(a2) RED(a3) RED(a4) RED(a5) RED(a6) RED(a7)
#undef RED
  if (grp == 0) {
    uint4 o;
    o.x = (unsigned int)f2bf(a0) | ((unsigned int)f2bf(a1) << 16);
    o.y = (unsigned int)f2bf(a2) | ((unsigned int)f2bf(a3) << 16);
    o.z = (unsigned int)f2bf(a4) | ((unsigned int)f2bf(a5) << 16);
    o.w = (unsigned int)f2bf(a6) | ((unsigned int)f2bf(a7) << 16);
    *(uint4*)(aggb + ((size_t)wid << 7) + (lb >> 1)) = o;
  }
}

// ---------------- per-graph segment sum (binary-search bounds) ----------------
__global__ __launch_bounds__(SDIM) void segsum_k(const unsigned short* __restrict__ sbf,
                                                 const int* __restrict__ batch,
                                                 int N, float* __restrict__ out) {
  const int g = blockIdx.x;
  __shared__ int se[2];
  if (threadIdx.x < 2) {
    const int target = g + threadIdx.x;
    int lo = 0, hi = N;
    while (lo < hi) {
      const int mid = (lo + hi) >> 1;
      if (batch[mid] < target) lo = mid + 1; else hi = mid;
    }
    se[threadIdx.x] = lo;
  }
  __syncthreads();
  const int s = se[0], e = se[1];
  const int j = threadIdx.x;
  float acc = 0.f;
  for (int i = s; i < e; ++i) acc += bf2f(sbf[(size_t)i * SDIM + j]);
  out[(size_t)g * SDIM + j] = acc;
}

extern "C" void kernel_launch(void* const* d_in, const int* in_sizes, int n_in,
                              void* d_out, int out_size, void* d_ws, size_t ws_size,
                              hipStream_t stream) {
  const float* W_msg = (const float*)d_in[1];
  const float* b_msg = (const float*)d_in[2];
  const float* W_upd = (const float*)d_in[3];
  const float* b_upd = (const float*)d_in[4];
  const int* edges = (const int*)d_in[5];
  const int* batch = (const int*)d_in[6];
  const int E = in_sizes[5] / 2;
  const int N = in_sizes[6];       // requires N <= 65536
  const int G = out_size / SDIM;
  const int R = in_sizes[2] / SDIM;
  const int WSZ = R * SDIM * SDIM;

  const int NB = (N + 127) >> 7;   // 128-node buckets

  const size_t NS = (size_t)N * SDIM;
  unsigned short* sbf = (unsigned short*)d_ws;     // NS
  unsigned short* msgb = sbf + NS;                 // NS
  unsigned short* aggb = msgb + NS;                // NS
  unsigned short* wmsgb = aggb + NS;               // WSZ
  unsigned short* wupdb = wmsgb + WSZ;             // WSZ (contiguous)
  float* cvec = (float*)(wupdb + WSZ);             // 128
  int* offs = (int*)(cvec + SDIM);                 // N
  int* oend = offs + N;                            // N
  int* bcursor = oend + N;                         // NB (zeroed in cast2c)
  unsigned int* pairBuf4 = (unsigned int*)(bcursor + NB);     // NB*BCAP u32
  unsigned short* csr = (unsigned short*)(pairBuf4 + (size_t)NB * BCAP);  // NB*BCAP u16

  const int* srcArr = edges;
  const int* dstArr = edges + E;

  const int nCast = (2 * WSZ / 4 + 255) / 256;
  cast2c_k<<<nCast + 2, 256, 0, stream>>>(W_msg, W_upd, wmsgb, WSZ,
                                          W_upd, b_msg, cvec, bcursor, NB, nCast);
  bucket_k<<<(E + EPB2 - 1) / EPB2, 256, 0, stream>>>(srcArr, dstArr, bcursor,
                                                      pairBuf4, E);
  fill3_k<<<NB, 512, 0, stream>>>(pairBuf4, bcursor, offs, oend, csr, N);

  const int gemmGrid = (N + 127) / 128;
  const int aggGrid = (N * 64 + 255) / 256;

  // round 1: init state + msg1 (fused)
  initmsg_k<<<gemmGrid, 512, 0, stream>>>(offs, oend, cvec, b_upd,
                                          wmsgb + (size_t)1 * SDIM * SDIM,
                                          b_msg + 1 * SDIM, sbf, msgb, N);
  agg_bf16_k<<<aggGrid, 256, 0, stream>>>(msgb, csr, offs, oend, aggb, N);
  for (int r = 1; r < R - 1; ++r) {
    updmsg_k<true><<<gemmGrid, 512, 0, stream>>>(
        aggb, wupdb + (size_t)r * SDIM * SDIM, b_upd + (size_t)r * SDIM, sbf,
        wmsgb + (size_t)(r + 1) * SDIM * SDIM, b_msg + (size_t)(r + 1) * SDIM, msgb, N);
    agg_bf16_k<<<aggGrid, 256, 0, stream>>>(msgb, csr, offs, oend, aggb, N);
  }
  updmsg_k<false><<<gemmGrid, 512, 0, stream>>>(
      aggb, wupdb + (size_t)(R - 1) * SDIM * SDIM, b_upd + (size_t)(R - 1) * SDIM, sbf,
      nullptr, nullptr, nullptr, N);

  segsum_k<<<G, SDIM, 0, stream>>>(sbf, batch, N, (float*)d_out);
}

// Round 16
// 308.545 us; speedup vs baseline: 1.0770x; 1.0770x over previous
//
#include <hip/hip_runtime.h>
#include <hip/hip_bf16.h>
#include <cstdint>
#include <cstddef>

#define SDIM 128
#define EPB2 4096   // edges per block in bucket_k
#define BCAP 4608   // per-bucket capacity (mean 4092 + 8 sigma)

typedef short bf16x8 __attribute__((ext_vector_type(8)));
typedef float f32x4 __attribute__((ext_vector_type(4)));

__device__ __forceinline__ unsigned short f2bf(float f) {
  unsigned int u = __float_as_uint(f);
  unsigned int r = (u + 0x7FFF + ((u >> 16) & 1)) >> 16;  // RNE
  return (unsigned short)r;
}
__device__ __forceinline__ float bf2f(unsigned short b) {
  return __uint_as_float(((unsigned int)b) << 16);
}

// ---------------- phase 1: bucket packed (d<<16|src) by dst>>7, capacity regions ----
__global__ __launch_bounds__(256) void bucket_k(const int* __restrict__ src,
                                                const int* __restrict__ dst,
                                                int* __restrict__ bcursor,
                                                unsigned int* __restrict__ pairBuf4,
                                                int E) {
  __shared__ unsigned int s_buf[EPB2];
  __shared__ int cnt[512], base[512], gbase[512];
  const int tid = threadIdx.x;
  const int e0 = blockIdx.x * EPB2;
  const int n = min(EPB2, E - e0);
  cnt[tid] = 0; cnt[tid + 256] = 0;
  __syncthreads();

  unsigned int pack_r[16];
  int rank_r[16], bkt_r[16];
  if (n == EPB2) {
    const int4* dp = (const int4*)(dst + e0 + tid * 16);
    const int4* sp = (const int4*)(src + e0 + tid * 16);
#pragma unroll
    for (int q = 0; q < 4; ++q) {
      const int4 dv = dp[q];
      const int4 sv = sp[q];
      const int dd[4] = {dv.x, dv.y, dv.z, dv.w};
      const int ss[4] = {sv.x, sv.y, sv.z, sv.w};
#pragma unroll
      for (int w = 0; w < 4; ++w) {
        const int u = q * 4 + w;
        const int b = dd[w] >> 7;
        bkt_r[u] = b;
        pack_r[u] = ((unsigned int)dd[w] << 16) | (unsigned int)ss[w];
        rank_r[u] = atomicAdd(&cnt[b], 1);
      }
    }
  } else {
#pragma unroll
    for (int u = 0; u < 16; ++u) {
      const int li = u * 256 + tid;
      bkt_r[u] = -1;
      if (li < n) {
        const int i = e0 + li;
        const int d = dst[i];
        const int b = d >> 7;
        bkt_r[u] = b;
        pack_r[u] = ((unsigned int)d << 16) | (unsigned int)src[i];
        rank_r[u] = atomicAdd(&cnt[b], 1);
      }
    }
  }
  __syncthreads();
  if (tid < 64) {
    int carry = 0;
#pragma unroll
    for (int chunk = 0; chunk < 512; chunk += 256) {
      const int j0 = chunk + tid * 4;
      const int c0 = cnt[j0], c1 = cnt[j0 + 1], c2 = cnt[j0 + 2], c3 = cnt[j0 + 3];
      const int s = c0 + c1 + c2 + c3;
      int incl = s;
#pragma unroll
      for (int off = 1; off < 64; off <<= 1) {
        int u = __shfl_up(incl, off, 64);
        if (tid >= off) incl += u;
      }
      const int e = carry + incl - s;
      base[j0] = e;
      base[j0 + 1] = e + c0;
      base[j0 + 2] = e + c0 + c1;
      base[j0 + 3] = e + c0 + c1 + c2;
      carry += __shfl(incl, 63, 64);
    }
  }
  __syncthreads();
  for (int b = tid; b < 512; b += 256)
    if (cnt[b] > 0) gbase[b] = atomicAdd(&bcursor[b], cnt[b]);
  __syncthreads();
#pragma unroll
  for (int u = 0; u < 16; ++u) {
    if (n == EPB2 || bkt_r[u] >= 0)
      s_buf[base[bkt_r[u]] + rank_r[u]] = pack_r[u];
  }
  __syncthreads();
  for (int i = tid; i < n; i += 256) {
    const unsigned int p = s_buf[i];
    const int b = (int)(p >> 23);
    pairBuf4[(size_t)b * BCAP + (size_t)(gbase[b] + (i - base[b]))] = p;
  }
}

// ---------------- phase 2: per-bucket hist + scan + rank/scatter (padded csr) -----
__global__ __launch_bounds__(512) void fill3_k(const unsigned int* __restrict__ pairBuf4,
                                               const int* __restrict__ bcursor,
                                               int* __restrict__ offs,
                                               int* __restrict__ oend,
                                               unsigned short* __restrict__ csr, int N) {
  const int b = blockIdx.x;
  const int rlo = b * BCAP;
  const int rhi = rlo + bcursor[b];
  const int lo_node = b << 7;
  __shared__ int hist[128], cur[128];
  const int tid = threadIdx.x;
  if (tid < 128) hist[tid] = 0;
  __syncthreads();
  for (int i = rlo + tid; i < rhi; i += 512)
    atomicAdd(&hist[(pairBuf4[i] >> 16) & 127], 1);
  __syncthreads();
  if (tid < 64) {
    const int j0 = tid * 2;
    const int h0 = hist[j0], h1 = hist[j0 + 1];
    const int s = h0 + h1;
    int incl = s;
#pragma unroll
    for (int off = 1; off < 64; off <<= 1) {
      int u = __shfl_up(incl, off, 64);
      if (tid >= off) incl += u;
    }
    const int e = rlo + incl - s;
    cur[j0] = e; cur[j0 + 1] = e + h0;
    const int n0 = lo_node + j0;
    if (n0 < N) { offs[n0] = e; oend[n0] = e + h0; }
    if (n0 + 1 < N) { offs[n0 + 1] = e + h0; oend[n0 + 1] = e + h0 + h1; }
  }
  __syncthreads();
  for (int i = rlo + tid; i < rhi; i += 512) {
    const unsigned int p = pairBuf4[i];
    const int pos = atomicAdd(&cur[(p >> 16) & 127], 1);
    csr[pos] = (unsigned short)p;
  }
}

// ---------------- fused weight cast + compute_c + bcursor zero --------------------
__global__ __launch_bounds__(256) void cast2c_k(const float* __restrict__ a,
                                                const float* __restrict__ b,
                                                unsigned short* __restrict__ out, int n,
                                                const float* __restrict__ W_upd0,
                                                const float* __restrict__ b_msg0,
                                                float* __restrict__ cvec,
                                                int* __restrict__ bcursor, int NB,
                                                int nCast) {
  if ((int)blockIdx.x == nCast) {
    __shared__ float m0[SDIM];
    const int j = threadIdx.x;
    if (j < SDIM) m0[j] = fmaxf(b_msg0[j], 0.f);
    __syncthreads();
    if (j < SDIM) {
      float s = 0.f;
      const float* wr = W_upd0 + (size_t)j * SDIM;
      for (int k = 0; k < SDIM; ++k) s += wr[k] * m0[k];
      cvec[j] = s;
    }
    return;
  }
  if ((int)blockIdx.x == nCast + 1) {
    for (int i = threadIdx.x; i < NB; i += 256) bcursor[i] = 0;
    return;
  }
  int i = (blockIdx.x * 256 + threadIdx.x) * 4;
  if (i >= 2 * n) return;
  const float* s = (i < n) ? (a + i) : (b + (i - n));
  float4 v = *(const float4*)s;
  ushort4 o;
  o.x = f2bf(v.x); o.y = f2bf(v.y); o.z = f2bf(v.z); o.w = f2bf(v.w);
  *(ushort4*)(out + i) = o;
}

// ---------------- fused init_state + first message GEMM (32 rows/wave, 256 thr) ---
__global__ __launch_bounds__(256) void initmsg_k(const int* __restrict__ offs,
                                                 const int* __restrict__ oend,
                                                 const float* __restrict__ cvec,
                                                 const float* __restrict__ bu0,
                                                 const unsigned short* __restrict__ Wm,
                                                 const float* __restrict__ bm,
                                                 unsigned short* __restrict__ sbf,
                                                 unsigned short* __restrict__ msgb, int N) {
  __shared__ unsigned short sT[4][32][136];
  const int tid = threadIdx.x, lane = tid & 63, wid = tid >> 6;
  const int r0 = blockIdx.x * 128 + wid * 32;
  const int kb = (lane >> 4) * 8;
  const int wrow = lane & 15;

  bf16x8 a[2][4];
#pragma unroll
  for (int m = 0; m < 2; ++m) {
    int arow = r0 + m * 16 + (lane & 15);
    const bool rowOk = arow < N;
    if (!rowOk) arow = N - 1;
    const float dn = (float)(oend[arow] - offs[arow]);
#pragma unroll
    for (int ks = 0; ks < 4; ++ks) {
      const int c0 = ks * 32 + kb;
#pragma unroll
      for (int q = 0; q < 8; ++q) {
        const float v = fmaxf(dn * cvec[c0 + q] + bu0[c0 + q], 0.f);
        a[m][ks][q] = (short)f2bf(v);
      }
      if (rowOk) *(bf16x8*)(sbf + (size_t)arow * SDIM + c0) = a[m][ks];
    }
  }

  f32x4 acc[2][8];
#pragma unroll
  for (int m = 0; m < 2; ++m)
#pragma unroll
    for (int jt = 0; jt < 8; ++jt) acc[m][jt] = (f32x4){0.f, 0.f, 0.f, 0.f};
#pragma unroll
  for (int ks = 0; ks < 4; ++ks) {
#pragma unroll
    for (int jt = 0; jt < 8; ++jt) {
      bf16x8 b = *(const bf16x8*)(Wm + (size_t)(jt * 16 + wrow) * SDIM + ks * 32 + kb);
      acc[0][jt] = __builtin_amdgcn_mfma_f32_16x16x32_bf16(a[0][ks], b, acc[0][jt], 0, 0, 0);
      acc[1][jt] = __builtin_amdgcn_mfma_f32_16x16x32_bf16(a[1][ks], b, acc[1][jt], 0, 0, 0);
    }
  }
  const int colw = lane & 15;
  const int rt0 = (lane >> 4) * 4;
#pragma unroll
  for (int m = 0; m < 2; ++m)
#pragma unroll
    for (int jt = 0; jt < 8; ++jt) {
      const float bj = bm[jt * 16 + colw];
#pragma unroll
      for (int r = 0; r < 4; ++r)
        sT[wid][m * 16 + rt0 + r][jt * 16 + colw] = f2bf(fmaxf(acc[m][jt][r] + bj, 0.f));
    }
  __syncthreads();
  const int vr = lane >> 4;
  const int vc = (lane & 15) * 8;
#pragma unroll
  for (int it = 0; it < 8; ++it) {
    const int lr = it * 4 + vr;
    const int row = r0 + lr;
    if (row < N)
      *(bf16x8*)(msgb + (size_t)row * SDIM + vc) = *(const bf16x8*)&sT[wid][lr][vc];
  }
}

// ---------------- fused update GEMM + (optional) next message GEMM (32 rows/wave) -
template <bool MSG>
__global__ __launch_bounds__(256) void updmsg_k(const unsigned short* __restrict__ aggb,
                                                const unsigned short* __restrict__ Wu,
                                                const float* __restrict__ bu,
                                                unsigned short* __restrict__ sbf,
                                                const unsigned short* __restrict__ Wm,
                                                const float* __restrict__ bm,
                                                unsigned short* __restrict__ msgb, int N) {
  __shared__ unsigned short sT[4][32][136];
  const int tid = threadIdx.x, lane = tid & 63, wid = tid >> 6;
  const int r0 = blockIdx.x * 128 + wid * 32;
  const int kb = (lane >> 4) * 8;
  const int wrow = lane & 15;

  bf16x8 a[2][4];
#pragma unroll
  for (int m = 0; m < 2; ++m) {
    int arow = r0 + m * 16 + (lane & 15);
    if (arow >= N) arow = N - 1;
#pragma unroll
    for (int ks = 0; ks < 4; ++ks)
      a[m][ks] = *(const bf16x8*)(aggb + (size_t)arow * SDIM + ks * 32 + kb);
  }

  f32x4 acc[2][8];
#pragma unroll
  for (int m = 0; m < 2; ++m)
#pragma unroll
    for (int jt = 0; jt < 8; ++jt) acc[m][jt] = (f32x4){0.f, 0.f, 0.f, 0.f};
#pragma unroll
  for (int ks = 0; ks < 4; ++ks) {
#pragma unroll
    for (int jt = 0; jt < 8; ++jt) {
      bf16x8 b = *(const bf16x8*)(Wu + (size_t)(jt * 16 + wrow) * SDIM + ks * 32 + kb);
      acc[0][jt] = __builtin_amdgcn_mfma_f32_16x16x32_bf16(a[0][ks], b, acc[0][jt], 0, 0, 0);
      acc[1][jt] = __builtin_amdgcn_mfma_f32_16x16x32_bf16(a[1][ks], b, acc[1][jt], 0, 0, 0);
    }
  }

  const int colw = lane & 15;
  const int rt0 = (lane >> 4) * 4;
#pragma unroll
  for (int m = 0; m < 2; ++m)
#pragma unroll
    for (int jt = 0; jt < 8; ++jt) {
      const float bj = bu[jt * 16 + colw];
#pragma unroll
      for (int r = 0; r < 4; ++r)
        sT[wid][m * 16 + rt0 + r][jt * 16 + colw] = f2bf(fmaxf(acc[m][jt][r] + bj, 0.f));
    }
  __syncthreads();

  // vectorized state RMW: 8 iterations x (16B load + 16B store), coalesced
  const int vr = lane >> 4;
  const int vc = (lane & 15) * 8;
#pragma unroll
  for (int it = 0; it < 8; ++it) {
    const int lr = it * 4 + vr;
    const int row = r0 + lr;
    if (row < N) {
      bf16x8 nw = *(const bf16x8*)&sT[wid][lr][vc];
      bf16x8 old = *(const bf16x8*)(sbf + (size_t)row * SDIM + vc);
      bf16x8 up;
#pragma unroll
      for (int q = 0; q < 8; ++q)
        up[q] = (short)f2bf(bf2f((unsigned short)old[q]) + bf2f((unsigned short)nw[q]));
      *(bf16x8*)(sbf + (size_t)row * SDIM + vc) = up;
      if (MSG) *(bf16x8*)&sT[wid][lr][vc] = up;
    }
  }

  if (MSG) {
    __syncthreads();
    f32x4 acc2[2][8];
#pragma unroll
    for (int m = 0; m < 2; ++m)
#pragma unroll
      for (int jt = 0; jt < 8; ++jt) acc2[m][jt] = (f32x4){0.f, 0.f, 0.f, 0.f};
#pragma unroll
    for (int ks = 0; ks < 4; ++ks) {
      bf16x8 a20 = *(const bf16x8*)&sT[wid][lane & 15][ks * 32 + kb];
      bf16x8 a21 = *(const bf16x8*)&sT[wid][16 + (lane & 15)][ks * 32 + kb];
#pragma unroll
      for (int jt = 0; jt < 8; ++jt) {
        bf16x8 b = *(const bf16x8*)(Wm + (size_t)(jt * 16 + wrow) * SDIM + ks * 32 + kb);
        acc2[0][jt] = __builtin_amdgcn_mfma_f32_16x16x32_bf16(a20, b, acc2[0][jt], 0, 0, 0);
        acc2[1][jt] = __builtin_amdgcn_mfma_f32_16x16x32_bf16(a21, b, acc2[1][jt], 0, 0, 0);
      }
    }
    __syncthreads();  // all A-frag reads done before overwrite
#pragma unroll
    for (int m = 0; m < 2; ++m)
#pragma unroll
      for (int jt = 0; jt < 8; ++jt) {
        const float bj = bm[jt * 16 + colw];
#pragma unroll
        for (int r = 0; r < 4; ++r)
          sT[wid][m * 16 + rt0 + r][jt * 16 + colw] = f2bf(fmaxf(acc2[m][jt][r] + bj, 0.f));
      }
    __syncthreads();
#pragma unroll
    for (int it = 0; it < 8; ++it) {
      const int lr = it * 4 + vr;
      const int row = r0 + lr;
      if (row < N)
        *(bf16x8*)(msgb + (size_t)row * SDIM + vc) = *(const bf16x8*)&sT[wid][lr][vc];
    }
  }
}

// ---------------- bf16 CSR aggregation: nt csr stream, 16-edge unroll -------------
__global__ __launch_bounds__(256) void agg_bf16_k(const unsigned short* __restrict__ msg,
                                                  const unsigned short* __restrict__ csr,
                                                  const int* __restrict__ offs,
                                                  const int* __restrict__ oend,
                                                  unsigned short* __restrict__ aggb, int N) {
  const int wid = (blockIdx.x * 256 + threadIdx.x) >> 6;
  if (wid >= N) return;
  const int lane = threadIdx.x & 63;
  const int grp = lane >> 4;
  const unsigned int lb = (unsigned int)((lane & 15) << 4);
  const char* base = (const char*)msg;
  const int e1 = oend[wid];
  int e = offs[wid];
  float a0 = 0.f, a1 = 0.f, a2 = 0.f, a3 = 0.f, a4 = 0.f, a5 = 0.f, a6 = 0.f, a7 = 0.f;
#define ACC8(v) { \
  a0 += __uint_as_float((v).x << 16); a1 += __uint_as_float((v).x & 0xFFFF0000u); \
  a2 += __uint_as_float((v).y << 16); a3 += __uint_as_float((v).y & 0xFFFF0000u); \
  a4 += __uint_as_float((v).z << 16); a5 += __uint_as_float((v).z & 0xFFFF0000u); \
  a6 += __uint_as_float((v).w << 16); a7 += __uint_as_float((v).w & 0xFFFF0000u); }
  for (; e + 16 <= e1; e += 16) {
    const unsigned int o0 = ((unsigned int)__builtin_nontemporal_load(csr + e + grp) << 8) | lb;
    const unsigned int o1 = ((unsigned int)__builtin_nontemporal_load(csr + e + 4 + grp) << 8) | lb;
    const unsigned int o2 = ((unsigned int)__builtin_nontemporal_load(csr + e + 8 + grp) << 8) | lb;
    const unsigned int o3 = ((unsigned int)__builtin_nontemporal_load(csr + e + 12 + grp) << 8) | lb;
    uint4 vA = *(const uint4*)(base + o0);
    uint4 vB = *(const uint4*)(base + o1);
    uint4 vC = *(const uint4*)(base + o2);
    uint4 vD = *(const uint4*)(base + o3);
    ACC8(vA) ACC8(vB) ACC8(vC) ACC8(vD)
  }
  for (; e + 4 <= e1; e += 4) {
    const unsigned int o0 = ((unsigned int)__builtin_nontemporal_load(csr + e + grp) << 8) | lb;
    uint4 v = *(const uint4*)(base + o0);
    ACC8(v)
  }
  if (e + grp < e1) {
    const unsigned int o0 = ((unsigned int)__builtin_nontemporal_load(csr + e + grp) << 8) | lb;
    uint4 v = *(const uint4*)(base + o0);
    ACC8(v)
  }
#undef ACC8
#define RED(x) x += __shfl_xor(x, 16, 64); x += __shfl_xor(x, 32, 64);
  RED(a0) RED(a1) RED(a2) RED(a3) RED(a4) RED(a5) RED(a6) RED(a7)
#undef RED
  if (grp == 0) {
    uint4 o;
    o.x = (unsigned int)f2bf(a0) | ((unsigned int)f2bf(a1) << 16);
    o.y = (unsigned int)f2bf(a2) | ((unsigned int)f2bf(a3) << 16);
    o.z = (unsigned int)f2bf(a4) | ((unsigned int)f2bf(a5) << 16);
    o.w = (unsigned int)f2bf(a6) | ((unsigned int)f2bf(a7) << 16);
    *(uint4*)(aggb + ((size_t)wid << 7) + (lb >> 1)) = o;
  }
}

// ---------------- per-graph segment sum (binary-search bounds) ----------------
__global__ __launch_bounds__(SDIM) void segsum_k(const unsigned short* __restrict__ sbf,
                                                 const int* __restrict__ batch,
                                                 int N, float* __restrict__ out) {
  const int g = blockIdx.x;
  __shared__ int se[2];
  if (threadIdx.x < 2) {
    const int target = g + threadIdx.x;
    int lo = 0, hi = N;
    while (lo < hi) {
      const int mid = (lo + hi) >> 1;
      if (batch[mid] < target) lo = mid + 1; else hi = mid;
    }
    se[threadIdx.x] = lo;
  }
  __syncthreads();
  const int s = se[0], e = se[1];
  const int j = threadIdx.x;
  float acc = 0.f;
  for (int i = s; i < e; ++i) acc += bf2f(sbf[(size_t)i * SDIM + j]);
  out[(size_t)g * SDIM + j] = acc;
}

extern "C" void kernel_launch(void* const* d_in, const int* in_sizes, int n_in,
                              void* d_out, int out_size, void* d_ws, size_t ws_size,
                              hipStream_t stream) {
  const float* W_msg = (const float*)d_in[1];
  const float* b_msg = (const float*)d_in[2];
  const float* W_upd = (const float*)d_in[3];
  const float* b_upd = (const float*)d_in[4];
  const int* edges = (const int*)d_in[5];
  const int* batch = (const int*)d_in[6];
  const int E = in_sizes[5] / 2;
  const int N = in_sizes[6];       // requires N <= 65536
  const int G = out_size / SDIM;
  const int R = in_sizes[2] / SDIM;
  const int WSZ = R * SDIM * SDIM;

  const int NB = (N + 127) >> 7;   // 128-node buckets

  const size_t NS = (size_t)N * SDIM;
  unsigned short* sbf = (unsigned short*)d_ws;     // NS
  unsigned short* msgb = sbf + NS;                 // NS
  unsigned short* aggb = msgb + NS;                // NS
  unsigned short* wmsgb = aggb + NS;               // WSZ
  unsigned short* wupdb = wmsgb + WSZ;             // WSZ (contiguous)
  float* cvec = (float*)(wupdb + WSZ);             // 128
  int* offs = (int*)(cvec + SDIM);                 // N
  int* oend = offs + N;                            // N
  int* bcursor = oend + N;                         // NB (zeroed in cast2c)
  unsigned int* pairBuf4 = (unsigned int*)(bcursor + NB);     // NB*BCAP u32
  unsigned short* csr = (unsigned short*)(pairBuf4 + (size_t)NB * BCAP);  // NB*BCAP u16

  const int* srcArr = edges;
  const int* dstArr = edges + E;

  const int nCast = (2 * WSZ / 4 + 255) / 256;
  cast2c_k<<<nCast + 2, 256, 0, stream>>>(W_msg, W_upd, wmsgb, WSZ,
                                          W_upd, b_msg, cvec, bcursor, NB, nCast);
  bucket_k<<<(E + EPB2 - 1) / EPB2, 256, 0, stream>>>(srcArr, dstArr, bcursor,
                                                      pairBuf4, E);
  fill3_k<<<NB, 512, 0, stream>>>(pairBuf4, bcursor, offs, oend, csr, N);

  const int gemmGrid = (N + 127) / 128;
  const int aggGrid = (N * 64 + 255) / 256;

  // round 1: init state + msg1 (fused)
  initmsg_k<<<gemmGrid, 256, 0, stream>>>(offs, oend, cvec, b_upd,
                                          wmsgb + (size_t)1 * SDIM * SDIM,
                                          b_msg + 1 * SDIM, sbf, msgb, N);
  agg_bf16_k<<<aggGrid, 256, 0, stream>>>(msgb, csr, offs, oend, aggb, N);
  for (int r = 1; r < R - 1; ++r) {
    updmsg_k<true><<<gemmGrid, 256, 0, stream>>>(
        aggb, wupdb + (size_t)r * SDIM * SDIM, b_upd + (size_t)r * SDIM, sbf,
        wmsgb + (size_t)(r + 1) * SDIM * SDIM, b_msg + (size_t)(r + 1) * SDIM, msgb, N);
    agg_bf16_k<<<aggGrid, 256, 0, stream>>>(msgb, csr, offs, oend, aggb, N);
  }
  updmsg_k<false><<<gemmGrid, 256, 0, stream>>>(
      aggb, wupdb + (size_t)(R - 1) * SDIM * SDIM, b_upd + (size_t)(R - 1) * SDIM, sbf,
      nullptr, nullptr, nullptr, N);

  segsum_k<<<G, SDIM, 0, stream>>>(sbf, batch, N, (float*)d_out);
}

// Round 17
// 301.614 us; speedup vs baseline: 1.1017x; 1.0230x over previous
//
#include <hip/hip_runtime.h>
#include <hip/hip_bf16.h>
#include <cstdint>
#include <cstddef>

#define SDIM 128
#define EPB2 4096   // edges per block in bucket_k
#define BCAP 4608   // per-bucket capacity (mean 4092 + 8 sigma)

typedef short bf16x8 __attribute__((ext_vector_type(8)));
typedef float f32x4 __attribute__((ext_vector_type(4)));

__device__ __forceinline__ unsigned short f2bf(float f) {
  unsigned int u = __float_as_uint(f);
  unsigned int r = (u + 0x7FFF + ((u >> 16) & 1)) >> 16;  // RNE
  return (unsigned short)r;
}
__device__ __forceinline__ float bf2f(unsigned short b) {
  return __uint_as_float(((unsigned int)b) << 16);
}

// ---------------- phase 1: bucket packed (d<<16|src) by dst>>7, capacity regions ----
__global__ __launch_bounds__(256) void bucket_k(const int* __restrict__ src,
                                                const int* __restrict__ dst,
                                                int* __restrict__ bcursor,
                                                unsigned int* __restrict__ pairBuf4,
                                                int E) {
  __shared__ unsigned int s_buf[EPB2];
  __shared__ int cnt[512], base[512], gbase[512];
  const int tid = threadIdx.x;
  const int e0 = blockIdx.x * EPB2;
  const int n = min(EPB2, E - e0);
  cnt[tid] = 0; cnt[tid + 256] = 0;
  __syncthreads();

  unsigned int pack_r[16];
  int rank_r[16], bkt_r[16];
  if (n == EPB2) {
    const int4* dp = (const int4*)(dst + e0 + tid * 16);
    const int4* sp = (const int4*)(src + e0 + tid * 16);
#pragma unroll
    for (int q = 0; q < 4; ++q) {
      const int4 dv = dp[q];
      const int4 sv = sp[q];
      const int dd[4] = {dv.x, dv.y, dv.z, dv.w};
      const int ss[4] = {sv.x, sv.y, sv.z, sv.w};
#pragma unroll
      for (int w = 0; w < 4; ++w) {
        const int u = q * 4 + w;
        const int b = dd[w] >> 7;
        bkt_r[u] = b;
        pack_r[u] = ((unsigned int)dd[w] << 16) | (unsigned int)ss[w];
        rank_r[u] = atomicAdd(&cnt[b], 1);
      }
    }
  } else {
#pragma unroll
    for (int u = 0; u < 16; ++u) {
      const int li = u * 256 + tid;
      bkt_r[u] = -1;
      if (li < n) {
        const int i = e0 + li;
        const int d = dst[i];
        const int b = d >> 7;
        bkt_r[u] = b;
        pack_r[u] = ((unsigned int)d << 16) | (unsigned int)src[i];
        rank_r[u] = atomicAdd(&cnt[b], 1);
      }
    }
  }
  __syncthreads();
  if (tid < 64) {
    int carry = 0;
#pragma unroll
    for (int chunk = 0; chunk < 512; chunk += 256) {
      const int j0 = chunk + tid * 4;
      const int c0 = cnt[j0], c1 = cnt[j0 + 1], c2 = cnt[j0 + 2], c3 = cnt[j0 + 3];
      const int s = c0 + c1 + c2 + c3;
      int incl = s;
#pragma unroll
      for (int off = 1; off < 64; off <<= 1) {
        int u = __shfl_up(incl, off, 64);
        if (tid >= off) incl += u;
      }
      const int e = carry + incl - s;
      base[j0] = e;
      base[j0 + 1] = e + c0;
      base[j0 + 2] = e + c0 + c1;
      base[j0 + 3] = e + c0 + c1 + c2;
      carry += __shfl(incl, 63, 64);
    }
  }
  __syncthreads();
  for (int b = tid; b < 512; b += 256)
    if (cnt[b] > 0) gbase[b] = atomicAdd(&bcursor[b], cnt[b]);
  __syncthreads();
#pragma unroll
  for (int u = 0; u < 16; ++u) {
    if (n == EPB2 || bkt_r[u] >= 0)
      s_buf[base[bkt_r[u]] + rank_r[u]] = pack_r[u];
  }
  __syncthreads();
  for (int i = tid; i < n; i += 256) {
    const unsigned int p = s_buf[i];
    const int b = (int)(p >> 23);
    pairBuf4[(size_t)b * BCAP + (size_t)(gbase[b] + (i - base[b]))] = p;
  }
}

// ---------------- phase 2: per-bucket hist + scan + rank/scatter (padded csr) -----
__global__ __launch_bounds__(512) void fill3_k(const unsigned int* __restrict__ pairBuf4,
                                               const int* __restrict__ bcursor,
                                               int* __restrict__ offs,
                                               int* __restrict__ oend,
                                               unsigned short* __restrict__ csr, int N) {
  const int b = blockIdx.x;
  const int rlo = b * BCAP;
  const int rhi = rlo + bcursor[b];
  const int lo_node = b << 7;
  __shared__ int hist[128], cur[128];
  const int tid = threadIdx.x;
  if (tid < 128) hist[tid] = 0;
  __syncthreads();
  for (int i = rlo + tid; i < rhi; i += 512)
    atomicAdd(&hist[(pairBuf4[i] >> 16) & 127], 1);
  __syncthreads();
  if (tid < 64) {
    const int j0 = tid * 2;
    const int h0 = hist[j0], h1 = hist[j0 + 1];
    const int s = h0 + h1;
    int incl = s;
#pragma unroll
    for (int off = 1; off < 64; off <<= 1) {
      int u = __shfl_up(incl, off, 64);
      if (tid >= off) incl += u;
    }
    const int e = rlo + incl - s;
    cur[j0] = e; cur[j0 + 1] = e + h0;
    const int n0 = lo_node + j0;
    if (n0 < N) { offs[n0] = e; oend[n0] = e + h0; }
    if (n0 + 1 < N) { offs[n0 + 1] = e + h0; oend[n0 + 1] = e + h0 + h1; }
  }
  __syncthreads();
  for (int i = rlo + tid; i < rhi; i += 512) {
    const unsigned int p = pairBuf4[i];
    const int pos = atomicAdd(&cur[(p >> 16) & 127], 1);
    csr[pos] = (unsigned short)p;
  }
}

// ---------------- fused weight cast + compute_c + bcursor zero --------------------
__global__ __launch_bounds__(256) void cast2c_k(const float* __restrict__ a,
                                                const float* __restrict__ b,
                                                unsigned short* __restrict__ out, int n,
                                                const float* __restrict__ W_upd0,
                                                const float* __restrict__ b_msg0,
                                                float* __restrict__ cvec,
                                                int* __restrict__ bcursor, int NB,
                                                int nCast) {
  if ((int)blockIdx.x == nCast) {
    __shared__ float m0[SDIM];
    const int j = threadIdx.x;
    if (j < SDIM) m0[j] = fmaxf(b_msg0[j], 0.f);
    __syncthreads();
    if (j < SDIM) {
      float s = 0.f;
      const float* wr = W_upd0 + (size_t)j * SDIM;
      for (int k = 0; k < SDIM; ++k) s += wr[k] * m0[k];
      cvec[j] = s;
    }
    return;
  }
  if ((int)blockIdx.x == nCast + 1) {
    for (int i = threadIdx.x; i < NB; i += 256) bcursor[i] = 0;
    return;
  }
  int i = (blockIdx.x * 256 + threadIdx.x) * 4;
  if (i >= 2 * n) return;
  const float* s = (i < n) ? (a + i) : (b + (i - n));
  float4 v = *(const float4*)s;
  ushort4 o;
  o.x = f2bf(v.x); o.y = f2bf(v.y); o.z = f2bf(v.z); o.w = f2bf(v.w);
  *(ushort4*)(out + i) = o;
}

// ---------------- fused init_state + first message GEMM (32 rows/wave, 256 thr) ---
__global__ __launch_bounds__(256) void initmsg_k(const int* __restrict__ offs,
                                                 const int* __restrict__ oend,
                                                 const float* __restrict__ cvec,
                                                 const float* __restrict__ bu0,
                                                 const unsigned short* __restrict__ Wm,
                                                 const float* __restrict__ bm,
                                                 unsigned short* __restrict__ sbf,
                                                 unsigned short* __restrict__ msgb, int N) {
  __shared__ unsigned short sT[4][32][136];
  const int tid = threadIdx.x, lane = tid & 63, wid = tid >> 6;
  const int r0 = blockIdx.x * 128 + wid * 32;
  const int kb = (lane >> 4) * 8;
  const int wrow = lane & 15;

  bf16x8 a[2][4];
#pragma unroll
  for (int m = 0; m < 2; ++m) {
    int arow = r0 + m * 16 + (lane & 15);
    const bool rowOk = arow < N;
    if (!rowOk) arow = N - 1;
    const float dn = (float)(oend[arow] - offs[arow]);
#pragma unroll
    for (int ks = 0; ks < 4; ++ks) {
      const int c0 = ks * 32 + kb;
#pragma unroll
      for (int q = 0; q < 8; ++q) {
        const float v = fmaxf(dn * cvec[c0 + q] + bu0[c0 + q], 0.f);
        a[m][ks][q] = (short)f2bf(v);
      }
      if (rowOk) *(bf16x8*)(sbf + (size_t)arow * SDIM + c0) = a[m][ks];
    }
  }

  f32x4 acc[2][8];
#pragma unroll
  for (int m = 0; m < 2; ++m)
#pragma unroll
    for (int jt = 0; jt < 8; ++jt) acc[m][jt] = (f32x4){0.f, 0.f, 0.f, 0.f};
#pragma unroll
  for (int ks = 0; ks < 4; ++ks) {
#pragma unroll
    for (int jt = 0; jt < 8; ++jt) {
      bf16x8 b = *(const bf16x8*)(Wm + (size_t)(jt * 16 + wrow) * SDIM + ks * 32 + kb);
      acc[0][jt] = __builtin_amdgcn_mfma_f32_16x16x32_bf16(a[0][ks], b, acc[0][jt], 0, 0, 0);
      acc[1][jt] = __builtin_amdgcn_mfma_f32_16x16x32_bf16(a[1][ks], b, acc[1][jt], 0, 0, 0);
    }
  }
  const int colw = lane & 15;
  const int rt0 = (lane >> 4) * 4;
#pragma unroll
  for (int m = 0; m < 2; ++m)
#pragma unroll
    for (int jt = 0; jt < 8; ++jt) {
      const float bj = bm[jt * 16 + colw];
#pragma unroll
      for (int r = 0; r < 4; ++r)
        sT[wid][m * 16 + rt0 + r][jt * 16 + colw] = f2bf(fmaxf(acc[m][jt][r] + bj, 0.f));
    }
  __syncthreads();
  const int vr = lane >> 4;
  const int vc = (lane & 15) * 8;
#pragma unroll
  for (int it = 0; it < 8; ++it) {
    const int lr = it * 4 + vr;
    const int row = r0 + lr;
    if (row < N)
      *(bf16x8*)(msgb + (size_t)row * SDIM + vc) = *(const bf16x8*)&sT[wid][lr][vc];
  }
}

// ---------------- fused update GEMM + (optional) next message GEMM (32 rows/wave) -
template <bool MSG>
__global__ __launch_bounds__(256) void updmsg_k(const unsigned short* __restrict__ aggb,
                                                const unsigned short* __restrict__ Wu,
                                                const float* __restrict__ bu,
                                                unsigned short* __restrict__ sbf,
                                                const unsigned short* __restrict__ Wm,
                                                const float* __restrict__ bm,
                                                unsigned short* __restrict__ msgb, int N) {
  __shared__ unsigned short sT[4][32][136];
  const int tid = threadIdx.x, lane = tid & 63, wid = tid >> 6;
  const int r0 = blockIdx.x * 128 + wid * 32;
  const int kb = (lane >> 4) * 8;
  const int wrow = lane & 15;

  bf16x8 a[2][4];
#pragma unroll
  for (int m = 0; m < 2; ++m) {
    int arow = r0 + m * 16 + (lane & 15);
    if (arow >= N) arow = N - 1;
#pragma unroll
    for (int ks = 0; ks < 4; ++ks)
      a[m][ks] = *(const bf16x8*)(aggb + (size_t)arow * SDIM + ks * 32 + kb);
  }

  f32x4 acc[2][8];
#pragma unroll
  for (int m = 0; m < 2; ++m)
#pragma unroll
    for (int jt = 0; jt < 8; ++jt) acc[m][jt] = (f32x4){0.f, 0.f, 0.f, 0.f};
#pragma unroll
  for (int ks = 0; ks < 4; ++ks) {
#pragma unroll
    for (int jt = 0; jt < 8; ++jt) {
      bf16x8 b = *(const bf16x8*)(Wu + (size_t)(jt * 16 + wrow) * SDIM + ks * 32 + kb);
      acc[0][jt] = __builtin_amdgcn_mfma_f32_16x16x32_bf16(a[0][ks], b, acc[0][jt], 0, 0, 0);
      acc[1][jt] = __builtin_amdgcn_mfma_f32_16x16x32_bf16(a[1][ks], b, acc[1][jt], 0, 0, 0);
    }
  }

  const int colw = lane & 15;
  const int rt0 = (lane >> 4) * 4;
#pragma unroll
  for (int m = 0; m < 2; ++m)
#pragma unroll
    for (int jt = 0; jt < 8; ++jt) {
      const float bj = bu[jt * 16 + colw];
#pragma unroll
      for (int r = 0; r < 4; ++r)
        sT[wid][m * 16 + rt0 + r][jt * 16 + colw] = f2bf(fmaxf(acc[m][jt][r] + bj, 0.f));
    }
  __syncthreads();

  // vectorized state RMW: 8 iterations x (16B load + 16B store), coalesced
  const int vr = lane >> 4;
  const int vc = (lane & 15) * 8;
#pragma unroll
  for (int it = 0; it < 8; ++it) {
    const int lr = it * 4 + vr;
    const int row = r0 + lr;
    if (row < N) {
      bf16x8 nw = *(const bf16x8*)&sT[wid][lr][vc];
      bf16x8 old = *(const bf16x8*)(sbf + (size_t)row * SDIM + vc);
      bf16x8 up;
#pragma unroll
      for (int q = 0; q < 8; ++q)
        up[q] = (short)f2bf(bf2f((unsigned short)old[q]) + bf2f((unsigned short)nw[q]));
      *(bf16x8*)(sbf + (size_t)row * SDIM + vc) = up;
      if (MSG) *(bf16x8*)&sT[wid][lr][vc] = up;
    }
  }

  if (MSG) {
    __syncthreads();
    f32x4 acc2[2][8];
#pragma unroll
    for (int m = 0; m < 2; ++m)
#pragma unroll
      for (int jt = 0; jt < 8; ++jt) acc2[m][jt] = (f32x4){0.f, 0.f, 0.f, 0.f};
#pragma unroll
    for (int ks = 0; ks < 4; ++ks) {
      bf16x8 a20 = *(const bf16x8*)&sT[wid][lane & 15][ks * 32 + kb];
      bf16x8 a21 = *(const bf16x8*)&sT[wid][16 + (lane & 15)][ks * 32 + kb];
#pragma unroll
      for (int jt = 0; jt < 8; ++jt) {
        bf16x8 b = *(const bf16x8*)(Wm + (size_t)(jt * 16 + wrow) * SDIM + ks * 32 + kb);
        acc2[0][jt] = __builtin_amdgcn_mfma_f32_16x16x32_bf16(a20, b, acc2[0][jt], 0, 0, 0);
        acc2[1][jt] = __builtin_amdgcn_mfma_f32_16x16x32_bf16(a21, b, acc2[1][jt], 0, 0, 0);
      }
    }
    __syncthreads();  // all A-frag reads done before overwrite
#pragma unroll
    for (int m = 0; m < 2; ++m)
#pragma unroll
      for (int jt = 0; jt < 8; ++jt) {
        const float bj = bm[jt * 16 + colw];
#pragma unroll
        for (int r = 0; r < 4; ++r)
          sT[wid][m * 16 + rt0 + r][jt * 16 + colw] = f2bf(fmaxf(acc2[m][jt][r] + bj, 0.f));
      }
    __syncthreads();
#pragma unroll
    for (int it = 0; it < 8; ++it) {
      const int lr = it * 4 + vr;
      const int row = r0 + lr;
      if (row < N)
        *(bf16x8*)(msgb + (size_t)row * SDIM + vc) = *(const bf16x8*)&sT[wid][lr][vc];
    }
  }
}

// ---------------- bf16 CSR aggregation: 32-bit offsets, 16-edge unroll ------------
__global__ __launch_bounds__(256) void agg_bf16_k(const unsigned short* __restrict__ msg,
                                                  const unsigned short* __restrict__ csr,
                                                  const int* __restrict__ offs,
                                                  const int* __restrict__ oend,
                                                  unsigned short* __restrict__ aggb, int N) {
  const int wid = (blockIdx.x * 256 + threadIdx.x) >> 6;
  if (wid >= N) return;
  const int lane = threadIdx.x & 63;
  const int grp = lane >> 4;
  const unsigned int lb = (unsigned int)((lane & 15) << 4);
  const char* base = (const char*)msg;
  const int e1 = oend[wid];
  int e = offs[wid];
  float a0 = 0.f, a1 = 0.f, a2 = 0.f, a3 = 0.f, a4 = 0.f, a5 = 0.f, a6 = 0.f, a7 = 0.f;
#define ACC8(v) { \
  a0 += __uint_as_float((v).x << 16); a1 += __uint_as_float((v).x & 0xFFFF0000u); \
  a2 += __uint_as_float((v).y << 16); a3 += __uint_as_float((v).y & 0xFFFF0000u); \
  a4 += __uint_as_float((v).z << 16); a5 += __uint_as_float((v).z & 0xFFFF0000u); \
  a6 += __uint_as_float((v).w << 16); a7 += __uint_as_float((v).w & 0xFFFF0000u); }
  for (; e + 16 <= e1; e += 16) {
    const unsigned int o0 = ((unsigned int)csr[e + grp] << 8) | lb;
    const unsigned int o1 = ((unsigned int)csr[e + 4 + grp] << 8) | lb;
    const unsigned int o2 = ((unsigned int)csr[e + 8 + grp] << 8) | lb;
    const unsigned int o3 = ((unsigned int)csr[e + 12 + grp] << 8) | lb;
    uint4 vA = *(const uint4*)(base + o0);
    uint4 vB = *(const uint4*)(base + o1);
    uint4 vC = *(const uint4*)(base + o2);
    uint4 vD = *(const uint4*)(base + o3);
    ACC8(vA) ACC8(vB) ACC8(vC) ACC8(vD)
  }
  for (; e + 4 <= e1; e += 4) {
    const unsigned int o0 = ((unsigned int)csr[e + grp] << 8) | lb;
    uint4 v = *(const uint4*)(base + o0);
    ACC8(v)
  }
  if (e + grp < e1) {
    const unsigned int o0 = ((unsigned int)csr[e + grp] << 8) | lb;
    uint4 v = *(const uint4*)(base + o0);
    ACC8(v)
  }
#undef ACC8
#define RED(x) x += __shfl_xor(x, 16, 64); x += __shfl_xor(x, 32, 64);
  RED(a0) RED(a1) RED(a2) RED(a3) RED(a4) RED(a5) RED(a6) RED(a7)
#undef RED
  if (grp == 0) {
    uint4 o;
    o.x = (unsigned int)f2bf(a0) | ((unsigned int)f2bf(a1) << 16);
    o.y = (unsigned int)f2bf(a2) | ((unsigned int)f2bf(a3) << 16);
    o.z = (unsigned int)f2bf(a4) | ((unsigned int)f2bf(a5) << 16);
    o.w = (unsigned int)f2bf(a6) | ((unsigned int)f2bf(a7) << 16);
    *(uint4*)(aggb + ((size_t)wid << 7) + (lb >> 1)) = o;
  }
}

// ---------------- per-graph segment sum (binary-search bounds) ----------------
__global__ __launch_bounds__(SDIM) void segsum_k(const unsigned short* __restrict__ sbf,
                                                 const int* __restrict__ batch,
                                                 int N, float* __restrict__ out) {
  const int g = blockIdx.x;
  __shared__ int se[2];
  if (threadIdx.x < 2) {
    const int target = g + threadIdx.x;
    int lo = 0, hi = N;
    while (lo < hi) {
      const int mid = (lo + hi) >> 1;
      if (batch[mid] < target) lo = mid + 1; else hi = mid;
    }
    se[threadIdx.x] = lo;
  }
  __syncthreads();
  const int s = se[0], e = se[1];
  const int j = threadIdx.x;
  float acc = 0.f;
  for (int i = s; i < e; ++i) acc += bf2f(sbf[(size_t)i * SDIM + j]);
  out[(size_t)g * SDIM + j] = acc;
}

extern "C" void kernel_launch(void* const* d_in, const int* in_sizes, int n_in,
                              void* d_out, int out_size, void* d_ws, size_t ws_size,
                              hipStream_t stream) {
  const float* W_msg = (const float*)d_in[1];
  const float* b_msg = (const float*)d_in[2];
  const float* W_upd = (const float*)d_in[3];
  const float* b_upd = (const float*)d_in[4];
  const int* edges = (const int*)d_in[5];
  const int* batch = (const int*)d_in[6];
  const int E = in_sizes[5] / 2;
  const int N = in_sizes[6];       // requires N <= 65536
  const int G = out_size / SDIM;
  const int R = in_sizes[2] / SDIM;
  const int WSZ = R * SDIM * SDIM;

  const int NB = (N + 127) >> 7;   // 128-node buckets

  const size_t NS = (size_t)N * SDIM;
  unsigned short* sbf = (unsigned short*)d_ws;     // NS
  unsigned short* msgb = sbf + NS;                 // NS
  unsigned short* aggb = msgb + NS;                // NS
  unsigned short* wmsgb = aggb + NS;               // WSZ
  unsigned short* wupdb = wmsgb + WSZ;             // WSZ (contiguous)
  float* cvec = (float*)(wupdb + WSZ);             // 128
  int* offs = (int*)(cvec + SDIM);                 // N
  int* oend = offs + N;                            // N
  int* bcursor = oend + N;                         // NB (zeroed in cast2c)
  unsigned int* pairBuf4 = (unsigned int*)(bcursor + NB);     // NB*BCAP u32
  unsigned short* csr = (unsigned short*)(pairBuf4 + (size_t)NB * BCAP);  // NB*BCAP u16

  const int* srcArr = edges;
  const int* dstArr = edges + E;

  const int nCast = (2 * WSZ / 4 + 255) / 256;
  cast2c_k<<<nCast + 2, 256, 0, stream>>>(W_msg, W_upd, wmsgb, WSZ,
                                          W_upd, b_msg, cvec, bcursor, NB, nCast);
  bucket_k<<<(E + EPB2 - 1) / EPB2, 256, 0, stream>>>(srcArr, dstArr, bcursor,
                                                      pairBuf4, E);
  fill3_k<<<NB, 512, 0, stream>>>(pairBuf4, bcursor, offs, oend, csr, N);

  const int gemmGrid = (N + 127) / 128;
  const int aggGrid = (N * 64 + 255) / 256;

  // round 1: init state + msg1 (fused)
  initmsg_k<<<gemmGrid, 256, 0, stream>>>(offs, oend, cvec, b_upd,
                                          wmsgb + (size_t)1 * SDIM * SDIM,
                                          b_msg + 1 * SDIM, sbf, msgb, N);
  agg_bf16_k<<<aggGrid, 256, 0, stream>>>(msgb, csr, offs, oend, aggb, N);
  for (int r = 1; r < R - 1; ++r) {
    updmsg_k<true><<<gemmGrid, 256, 0, stream>>>(
        aggb, wupdb + (size_t)r * SDIM * SDIM, b_upd + (size_t)r * SDIM, sbf,
        wmsgb + (size_t)(r + 1) * SDIM * SDIM, b_msg + (size_t)(r + 1) * SDIM, msgb, N);
    agg_bf16_k<<<aggGrid, 256, 0, stream>>>(msgb, csr, offs, oend, aggb, N);
  }
  updmsg_k<false><<<gemmGrid, 256, 0, stream>>>(
      aggb, wupdb + (size_t)(R - 1) * SDIM * SDIM, b_upd + (size_t)(R - 1) * SDIM, sbf,
      nullptr, nullptr, nullptr, N);

  segsum_k<<<G, SDIM, 0, stream>>>(sbf, batch, N, (float*)d_out);
}